// Round 9
// baseline (2733.264 us; speedup 1.0000x reference)
//
#include <hip/hip_runtime.h>
#include <cstdint>
#include <cstddef>

#define GN    32768
#define GG    64
#define NNODE 512
#define EE    256
#define LL    4
#define DFFN  2048
#define NHH   8
#define HD    32
#define NEDGE 524288
#define KSEL  128
#define DIN   128

typedef __attribute__((ext_vector_type(8))) short short8;
typedef __attribute__((ext_vector_type(4))) float floatx4;

// ---- bf16 helpers (RNE) ---------------------------------------------------
__device__ __forceinline__ unsigned short f2bf(float x) {
  unsigned u = __float_as_uint(x);
  u = (u + 0x7FFFu + ((u >> 16) & 1u)) >> 16;
  return (unsigned short)u;
}
__device__ __forceinline__ float bf2f(unsigned short u) {
  return __uint_as_float((unsigned)u << 16);
}
__device__ __forceinline__ unsigned pack_split(float v) {
  unsigned short hb = f2bf(v);
  unsigned short lb = f2bf(v - bf2f(hb));
  return (unsigned)hb | ((unsigned)lb << 16);
}

// async global->LDS, 16B per lane (LDS dst must be wave-uniform base + lane*16)
__device__ __forceinline__ void ld_lds16(const ushort* g, ushort* l) {
  __builtin_amdgcn_global_load_lds(
      (const __attribute__((address_space(1))) unsigned int*)g,
      (__attribute__((address_space(3))) unsigned int*)l, 16, 0, 0);
}

// ---------------------------------------------------------------------------
// split fp32 -> (hi, lo) bf16 pair, 4 elements/thread
// ---------------------------------------------------------------------------
__global__ __launch_bounds__(256) void split_kernel(const float* __restrict__ in,
                                                    ushort* __restrict__ hi,
                                                    ushort* __restrict__ lo, int n4) {
  int i = blockIdx.x * 256 + threadIdx.x;
  if (i >= n4) return;
  float4 v = ((const float4*)in)[i];
  ushort4 hv, lv;
  float t[4] = {v.x, v.y, v.z, v.w};
  unsigned short hb;
  hb = f2bf(t[0]); hv.x = hb; lv.x = f2bf(t[0] - bf2f(hb));
  hb = f2bf(t[1]); hv.y = hb; lv.y = f2bf(t[1] - bf2f(hb));
  hb = f2bf(t[2]); hv.z = hb; lv.z = f2bf(t[2] - bf2f(hb));
  hb = f2bf(t[3]); hv.w = hb; lv.w = f2bf(t[3] - bf2f(hb));
  ((ushort4*)hi)[i] = hv;
  ((ushort4*)lo)[i] = lv;
}

// ---------------------------------------------------------------------------
// Split-bf16 MFMA GEMM: C[M,N] = split(A)[M,K] @ split(B)[N,K]^T (+bias / +=C)
// Strided A/B (lda/ldb) so K-slices of larger matrices can be addressed.
// XOR-swizzled LDS: frag b128 reads hit 8 banks (2-way, free).
// MODE bit0: fp32 C; bit1: split bf16 C. ACC: accumulate into Cf (no bias).
// VT: also scatter cols>=512 into vt[].
// ---------------------------------------------------------------------------
template <int BM, int BN, int MODE, bool RELU, bool VT, bool ACC>
__global__ __launch_bounds__(256) void mm_split(
    const ushort* __restrict__ a_hi, const ushort* __restrict__ a_lo,
    const ushort* __restrict__ b_hi, const ushort* __restrict__ b_lo,
    const float* __restrict__ bias,
    float* __restrict__ Cf, ushort* __restrict__ c_hi, ushort* __restrict__ c_lo,
    ushort* __restrict__ vth, ushort* __restrict__ vtl,
    int M, int N, int K, int lda, int ldb) {
  constexpr int MI = BM / 32;
  constexpr int NJ = BN / 32;
  __shared__ ushort As[2][BM * 32];
  __shared__ ushort Bs[2][BN * 32];
  const int tid = threadIdx.x;
  const int w = tid >> 6, lane = tid & 63;
  const int wm = (w >> 1) * (BM / 2), wn = (w & 1) * (BN / 2);
  const int bm = blockIdx.y * BM, bn = blockIdx.x * BN;
  const int lrow = lane & 15, lquad = lane >> 4;

  floatx4 acc[MI][NJ];
  floatx4 zz = {0.f, 0.f, 0.f, 0.f};
#pragma unroll
  for (int i = 0; i < MI; ++i)
#pragma unroll
    for (int j = 0; j < NJ; ++j) acc[i][j] = zz;

  const int arow = tid >> 2;
  const int acol = (((tid & 3) ^ ((arow >> 1) & 3)) << 3);  // swizzled source col
  const ushort* pah = a_hi + (size_t)(bm + arow) * lda + acol;
  const ushort* pal = a_lo + (size_t)(bm + arow) * lda + acol;
  const ushort* pbh = b_hi + (size_t)(bn + arow) * ldb + acol;
  const ushort* pbl = b_lo + (size_t)(bn + arow) * ldb + acol;

  for (int k0 = 0; k0 < K; k0 += 32) {
    __syncthreads();
#pragma unroll
    for (int s = 0; s < BM / 64; ++s) {
      ld_lds16(pah + (size_t)s * 64 * lda + k0, &As[0][s * 2048 + tid * 8]);
      ld_lds16(pal + (size_t)s * 64 * lda + k0, &As[1][s * 2048 + tid * 8]);
    }
#pragma unroll
    for (int s = 0; s < BN / 64; ++s) {
      ld_lds16(pbh + (size_t)s * 64 * ldb + k0, &Bs[0][s * 2048 + tid * 8]);
      ld_lds16(pbl + (size_t)s * 64 * ldb + k0, &Bs[1][s * 2048 + tid * 8]);
    }
    __syncthreads();
    short8 ah[MI], al[MI], bh[NJ], bl[NJ];
#pragma unroll
    for (int i = 0; i < MI; ++i) {
      int rr = wm + i * 16 + lrow;
      int r = rr * 32 + ((lquad ^ ((rr >> 1) & 3)) << 3);
      ah[i] = *(const short8*)&As[0][r];
      al[i] = *(const short8*)&As[1][r];
    }
#pragma unroll
    for (int j = 0; j < NJ; ++j) {
      int rr = wn + j * 16 + lrow;
      int r = rr * 32 + ((lquad ^ ((rr >> 1) & 3)) << 3);
      bh[j] = *(const short8*)&Bs[0][r];
      bl[j] = *(const short8*)&Bs[1][r];
    }
#pragma unroll
    for (int i = 0; i < MI; ++i)
#pragma unroll
      for (int j = 0; j < NJ; ++j) {
        acc[i][j] = __builtin_amdgcn_mfma_f32_16x16x32_bf16(al[i], bh[j], acc[i][j], 0, 0, 0);
        acc[i][j] = __builtin_amdgcn_mfma_f32_16x16x32_bf16(ah[i], bl[j], acc[i][j], 0, 0, 0);
        acc[i][j] = __builtin_amdgcn_mfma_f32_16x16x32_bf16(ah[i], bh[j], acc[i][j], 0, 0, 0);
      }
  }

#pragma unroll
  for (int j = 0; j < NJ; ++j) {
    int col = bn + wn + j * 16 + lrow;
    float bj = ACC ? 0.0f : bias[col];
#pragma unroll
    for (int i = 0; i < MI; ++i) {
      int row0 = bm + wm + i * 16 + lquad * 4;
#pragma unroll
      for (int r = 0; r < 4; ++r) {
        size_t off = (size_t)(row0 + r) * N + col;
        float v = acc[i][j][r] + bj;
        if constexpr (ACC) v += Cf[off];
        if (RELU) v = fmaxf(v, 0.0f);
        if constexpr (MODE & 1) Cf[off] = v;
        if constexpr (MODE & 2) {
          unsigned short hb = f2bf(v);
          unsigned short lb = f2bf(v - bf2f(hb));
          c_hi[off] = hb;
          c_lo[off] = lb;
          if constexpr (VT) {
            if (col >= 512) {
              int hd = col - 512;
              int row = row0 + r;
              size_t vo = ((size_t)((row >> 9) * 8 + (hd >> 5)) * 32 + (hd & 31)) * 512 + (row & 511);
              vth[vo] = hb;
              vtl[vo] = lb;
            }
          }
        }
      }
    }
  }
}

// ---------------------------------------------------------------------------
// Split GEMM + bias + residual + LayerNorm fused epilogue (BM=32; K=256
// out-proj only — for long K the barrier:MFMA ratio loses, measured r5-r7)
// ---------------------------------------------------------------------------
__global__ __launch_bounds__(256) void mm_ln(
    const ushort* __restrict__ a_hi, const ushort* __restrict__ a_lo,
    const ushort* __restrict__ b_hi, const ushort* __restrict__ b_lo,
    const float* __restrict__ bias, const float* __restrict__ lnw,
    const float* __restrict__ lnb, float* __restrict__ hbuf,
    ushort* __restrict__ hhi, ushort* __restrict__ hlo, int K) {
  __shared__ ushort As[2][32 * 32];
  __shared__ ushort Bs[2][256 * 32];
  __shared__ float rsum[32], rsq[32], muA[32], rsA[32];
  const int tid = threadIdx.x;
  const int w = tid >> 6, lane = tid & 63;
  const int wn = w * 64;
  const int bm = blockIdx.x * 32;
  const int lr = lane & 15, quad = lane >> 4;

  floatx4 acc[2][4];
  floatx4 zz = {0.f, 0.f, 0.f, 0.f};
#pragma unroll
  for (int i = 0; i < 2; ++i)
#pragma unroll
    for (int j = 0; j < 4; ++j) acc[i][j] = zz;

  if (tid < 32) { rsum[tid] = 0.f; rsq[tid] = 0.f; }

  const int aidx = tid & 127;
  const int arow = aidx >> 2;
  const int aacol = (((aidx & 3) ^ ((arow >> 1) & 3)) << 3);
  const ushort* pa = ((tid >> 7) ? a_lo : a_hi) + (size_t)(bm + arow) * K + aacol;
  ushort* adst = &As[tid >> 7][aidx * 8];
  const int brow = tid >> 2;
  const int bcol = (((tid & 3) ^ ((brow >> 1) & 3)) << 3);

  for (int k0 = 0; k0 < K; k0 += 32) {
    __syncthreads();
    ld_lds16(pa + k0, adst);
#pragma unroll
    for (int s = 0; s < 4; ++s) {
      ld_lds16(b_hi + (size_t)(s * 64 + brow) * K + bcol + k0, &Bs[0][s * 2048 + tid * 8]);
      ld_lds16(b_lo + (size_t)(s * 64 + brow) * K + bcol + k0, &Bs[1][s * 2048 + tid * 8]);
    }
    __syncthreads();
    short8 ah[2], al[2], bh[4], bl[4];
#pragma unroll
    for (int i = 0; i < 2; ++i) {
      int rr = i * 16 + lr;
      int r = rr * 32 + ((quad ^ ((rr >> 1) & 3)) << 3);
      ah[i] = *(const short8*)&As[0][r];
      al[i] = *(const short8*)&As[1][r];
    }
#pragma unroll
    for (int j = 0; j < 4; ++j) {
      int rr = wn + j * 16 + lr;
      int r = rr * 32 + ((quad ^ ((rr >> 1) & 3)) << 3);
      bh[j] = *(const short8*)&Bs[0][r];
      bl[j] = *(const short8*)&Bs[1][r];
    }
#pragma unroll
    for (int i = 0; i < 2; ++i)
#pragma unroll
      for (int j = 0; j < 4; ++j) {
        acc[i][j] = __builtin_amdgcn_mfma_f32_16x16x32_bf16(al[i], bh[j], acc[i][j], 0, 0, 0);
        acc[i][j] = __builtin_amdgcn_mfma_f32_16x16x32_bf16(ah[i], bl[j], acc[i][j], 0, 0, 0);
        acc[i][j] = __builtin_amdgcn_mfma_f32_16x16x32_bf16(ah[i], bh[j], acc[i][j], 0, 0, 0);
      }
  }

  // ---- epilogue: v = acc + bias + residual; row LN; write h + split ----
#pragma unroll
  for (int i = 0; i < 2; ++i) {
#pragma unroll
    for (int r = 0; r < 4; ++r) {
      int ridx = i * 16 + quad * 4 + r;
      float sp = 0.f, qp = 0.f;
#pragma unroll
      for (int j = 0; j < 4; ++j) {
        int col = wn + j * 16 + lr;
        float v = acc[i][j][r] + bias[col] + hbuf[(size_t)(bm + ridx) * EE + col];
        acc[i][j][r] = v;
        sp += v;
        qp += v * v;
      }
#pragma unroll
      for (int m = 1; m < 16; m <<= 1) { sp += __shfl_xor(sp, m); qp += __shfl_xor(qp, m); }
      if (lr == 0) { atomicAdd(&rsum[ridx], sp); atomicAdd(&rsq[ridx], qp); }
    }
  }
  __syncthreads();
  if (tid < 32) {
    float mu = rsum[tid] * (1.0f / 256.0f);
    float var = rsq[tid] * (1.0f / 256.0f) - mu * mu;
    muA[tid] = mu;
    rsA[tid] = 1.0f / sqrtf(var + 1e-5f);
  }
  __syncthreads();
#pragma unroll
  for (int i = 0; i < 2; ++i) {
#pragma unroll
    for (int r = 0; r < 4; ++r) {
      int ridx = i * 16 + quad * 4 + r;
      float mu = muA[ridx], rsv = rsA[ridx];
#pragma unroll
      for (int j = 0; j < 4; ++j) {
        int col = wn + j * 16 + lr;
        float o = (acc[i][j][r] - mu) * rsv * lnw[col] + lnb[col];
        size_t off = (size_t)(bm + ridx) * EE + col;
        hbuf[off] = o;
        unsigned short hb = f2bf(o);
        hhi[off] = hb;
        hlo[off] = f2bf(o - bf2f(hb));
      }
    }
  }
}

// ---------------------------------------------------------------------------
// h = LN(h + t)*w + b ; also writes split(h). One wave per row.
// ---------------------------------------------------------------------------
__global__ __launch_bounds__(256) void ln_res_kernel(float* __restrict__ h,
                                                     const float* __restrict__ t,
                                                     const float* __restrict__ w,
                                                     const float* __restrict__ b,
                                                     ushort* __restrict__ h_hi,
                                                     ushort* __restrict__ h_lo) {
  int row = blockIdx.x * 4 + (threadIdx.x >> 6);
  int lane = threadIdx.x & 63;
  size_t off = (size_t)row * EE + (lane << 2);
  float4 hv = *(const float4*)&h[off];
  float4 tv = *(const float4*)&t[off];
  float v0 = hv.x + tv.x, v1 = hv.y + tv.y, v2 = hv.z + tv.z, v3 = hv.w + tv.w;
  float s = (v0 + v1) + (v2 + v3);
#pragma unroll
  for (int m = 32; m > 0; m >>= 1) s += __shfl_xor(s, m);
  float mu = s * (1.0f / 256.0f);
  float d0 = v0 - mu, d1 = v1 - mu, d2 = v2 - mu, d3 = v3 - mu;
  float s2 = (d0 * d0 + d1 * d1) + (d2 * d2 + d3 * d3);
#pragma unroll
  for (int m = 32; m > 0; m >>= 1) s2 += __shfl_xor(s2, m);
  float rs = 1.0f / sqrtf(s2 * (1.0f / 256.0f) + 1e-5f);
  float4 wv = *(const float4*)&w[lane << 2];
  float4 bv = *(const float4*)&b[lane << 2];
  float4 o;
  o.x = d0 * rs * wv.x + bv.x;
  o.y = d1 * rs * wv.y + bv.y;
  o.z = d2 * rs * wv.z + bv.z;
  o.w = d3 * rs * wv.w + bv.w;
  *(float4*)&h[off] = o;
  ushort4 hb4, lb4;
  unsigned short hb;
  hb = f2bf(o.x); hb4.x = hb; lb4.x = f2bf(o.x - bf2f(hb));
  hb = f2bf(o.y); hb4.y = hb; lb4.y = f2bf(o.y - bf2f(hb));
  hb = f2bf(o.z); hb4.z = hb; lb4.z = f2bf(o.z - bf2f(hb));
  hb = f2bf(o.w); hb4.w = hb; lb4.w = f2bf(o.w - bf2f(hb));
  *(ushort4*)&h_hi[off] = hb4;
  *(ushort4*)&h_lo[off] = lb4;
}

// ---------------------------------------------------------------------------
// MFMA flash attention. 128 q-rows per block processed as 2 sequential 16-row
// m-tiles per wave (state duplicated, structure per-tile unchanged — r5's
// hoisted variant blew VGPR; this loops). 64-key K-tiles, slim LDS (~36.9 KB)
// -> 4 blocks/CU. Grid (qt, hh, g) — r7 ordering, empirically best L2 policy.
// ---------------------------------------------------------------------------
__global__ __launch_bounds__(256) void attn_mfma(const ushort* __restrict__ qh,
                                                 const ushort* __restrict__ ql,
                                                 const ushort* __restrict__ vth,
                                                 const ushort* __restrict__ vtl,
                                                 ushort* __restrict__ o_hi,
                                                 ushort* __restrict__ o_lo) {
  __shared__ ushort Ks[2][64 * 40];
  __shared__ ushort Vt[2][32 * 72];
  __shared__ unsigned Pint[4][16 * 68];
  const int tid = threadIdx.x;
  const int w = tid >> 6, lane = tid & 63, c = lane & 15, quad = lane >> 4;
  const int qt = blockIdx.x, hh = blockIdx.y, g = blockIdx.z;
  const size_t g512 = (size_t)g * 512;
  const size_t vtbase = (size_t)(g * 8 + hh) * 32 * 512;
  const float scale = 0.17677669529663687f * 1.44269504088896340f;  // /sqrt(32)*log2e

  short8 qfh[2], qfl[2];
#pragma unroll
  for (int mi = 0; mi < 2; ++mi) {
    size_t qnode = g512 + qt * 128 + mi * 64 + w * 16 + c;
    qfh[mi] = *(const short8*)(qh + qnode * 768 + hh * 32 + quad * 8);
    qfl[mi] = *(const short8*)(ql + qnode * 768 + hh * 32 + quad * 8);
  }

  floatx4 O[2][2];
  floatx4 zz = {0.f, 0.f, 0.f, 0.f};
  O[0][0] = zz; O[0][1] = zz; O[1][0] = zz; O[1][1] = zz;
  float mrow[2][4], lrow[2][4];
#pragma unroll
  for (int mi = 0; mi < 2; ++mi)
#pragma unroll
    for (int r = 0; r < 4; ++r) { mrow[mi][r] = -3e38f; lrow[mi][r] = 0.f; }

  const int skey = tid >> 2, sdc = (tid & 3) << 3;
  const int sd = tid >> 3, skc = (tid & 7) << 3;
  short8 stg[4];
  auto load_tile = [&](int kb) {
    size_t go = (g512 + kb + skey) * 768 + 256 + hh * 32 + sdc;
    stg[0] = *(const short8*)(qh + go);
    stg[1] = *(const short8*)(ql + go);
    size_t vo = vtbase + (size_t)sd * 512 + kb + skc;
    stg[2] = *(const short8*)(vth + vo);
    stg[3] = *(const short8*)(vtl + vo);
  };
  load_tile(0);

  for (int t = 0; t < 8; ++t) {
    if (t) __syncthreads();
    *(short8*)&Ks[0][skey * 40 + sdc] = stg[0];
    *(short8*)&Ks[1][skey * 40 + sdc] = stg[1];
    *(short8*)&Vt[0][sd * 72 + skc] = stg[2];
    *(short8*)&Vt[1][sd * 72 + skc] = stg[3];
    __syncthreads();
    if (t < 7) load_tile((t + 1) * 64);

#pragma unroll
    for (int mi = 0; mi < 2; ++mi) {
      floatx4 S[4];
#pragma unroll
      for (int n = 0; n < 4; ++n) {
        int r = (n * 16 + c) * 40 + quad * 8;
        short8 kfh = *(const short8*)&Ks[0][r];
        short8 kfl = *(const short8*)&Ks[1][r];
        floatx4 s = {0.f, 0.f, 0.f, 0.f};
        s = __builtin_amdgcn_mfma_f32_16x16x32_bf16(qfh[mi], kfl, s, 0, 0, 0);
        s = __builtin_amdgcn_mfma_f32_16x16x32_bf16(qfl[mi], kfh, s, 0, 0, 0);
        s = __builtin_amdgcn_mfma_f32_16x16x32_bf16(qfh[mi], kfh, s, 0, 0, 0);
#pragma unroll
        for (int r2 = 0; r2 < 4; ++r2) s[r2] *= scale;
        S[n] = s;
      }
      float corr[4];
#pragma unroll
      for (int r = 0; r < 4; ++r) {
        float mx = S[0][r];
#pragma unroll
        for (int n = 1; n < 4; ++n) mx = fmaxf(mx, S[n][r]);
#pragma unroll
        for (int msk = 1; msk < 16; msk <<= 1) mx = fmaxf(mx, __shfl_xor(mx, msk));
        float mn = fmaxf(mrow[mi][r], mx);
        corr[r] = exp2f(mrow[mi][r] - mn);
        mrow[mi][r] = mn;
      }
      float rs[4] = {0.f, 0.f, 0.f, 0.f};
#pragma unroll
      for (int n = 0; n < 4; ++n) {
#pragma unroll
        for (int r = 0; r < 4; ++r) {
          float pp = exp2f(S[n][r] - mrow[mi][r]);
          rs[r] += pp;
          Pint[w][(quad * 4 + r) * 68 + n * 16 + c] = pack_split(pp);
        }
      }
#pragma unroll
      for (int r = 0; r < 4; ++r) {
        float t2 = rs[r];
#pragma unroll
        for (int msk = 1; msk < 16; msk <<= 1) t2 += __shfl_xor(t2, msk);
        lrow[mi][r] = lrow[mi][r] * corr[r] + t2;
        O[mi][0][r] *= corr[r];
        O[mi][1][r] *= corr[r];
      }
#pragma unroll
      for (int ks = 0; ks < 2; ++ks) {
        const unsigned* pp = &Pint[w][c * 68 + ks * 32 + quad * 8];
        uint4 a = *(const uint4*)pp;
        uint4 b = *(const uint4*)(pp + 4);
        union { short8 s; unsigned u[4]; } ph, pl;
        ph.u[0] = (a.x & 0xFFFFu) | (a.y << 16);
        ph.u[1] = (a.z & 0xFFFFu) | (a.w << 16);
        ph.u[2] = (b.x & 0xFFFFu) | (b.y << 16);
        ph.u[3] = (b.z & 0xFFFFu) | (b.w << 16);
        pl.u[0] = (a.x >> 16) | (a.y & 0xFFFF0000u);
        pl.u[1] = (a.z >> 16) | (a.w & 0xFFFF0000u);
        pl.u[2] = (b.x >> 16) | (b.y & 0xFFFF0000u);
        pl.u[3] = (b.z >> 16) | (b.w & 0xFFFF0000u);
        int r0 = c * 72 + ks * 32 + quad * 8;
        int r1 = (16 + c) * 72 + ks * 32 + quad * 8;
        short8 v0h = *(const short8*)&Vt[0][r0];
        short8 v0l = *(const short8*)&Vt[1][r0];
        short8 v1h = *(const short8*)&Vt[0][r1];
        short8 v1l = *(const short8*)&Vt[1][r1];
        O[mi][0] = __builtin_amdgcn_mfma_f32_16x16x32_bf16(ph.s, v0l, O[mi][0], 0, 0, 0);
        O[mi][0] = __builtin_amdgcn_mfma_f32_16x16x32_bf16(pl.s, v0h, O[mi][0], 0, 0, 0);
        O[mi][0] = __builtin_amdgcn_mfma_f32_16x16x32_bf16(ph.s, v0h, O[mi][0], 0, 0, 0);
        O[mi][1] = __builtin_amdgcn_mfma_f32_16x16x32_bf16(ph.s, v1l, O[mi][1], 0, 0, 0);
        O[mi][1] = __builtin_amdgcn_mfma_f32_16x16x32_bf16(pl.s, v1h, O[mi][1], 0, 0, 0);
        O[mi][1] = __builtin_amdgcn_mfma_f32_16x16x32_bf16(ph.s, v1h, O[mi][1], 0, 0, 0);
      }
    }
  }

#pragma unroll
  for (int mi = 0; mi < 2; ++mi) {
#pragma unroll
    for (int r = 0; r < 4; ++r) {
      float inv = 1.0f / lrow[mi][r];
      size_t node = g512 + qt * 128 + mi * 64 + w * 16 + quad * 4 + r;
      size_t off0 = node * EE + hh * 32 + c;
      float v0 = O[mi][0][r] * inv;
      float v1 = O[mi][1][r] * inv;
      unsigned short hb0 = f2bf(v0), hb1 = f2bf(v1);
      o_hi[off0] = hb0;       o_lo[off0] = f2bf(v0 - bf2f(hb0));
      o_hi[off0 + 16] = hb1;  o_lo[off0 + 16] = f2bf(v1 - bf2f(hb1));
    }
  }
}

// ---------------------------------------------------------------------------
__global__ __launch_bounds__(256) void score_kernel(const float* __restrict__ h,
                                                    const float* __restrict__ sw,
                                                    const float* __restrict__ sb,
                                                    float* __restrict__ probs) {
  int row = blockIdx.x * 4 + (threadIdx.x >> 6);
  int lane = threadIdx.x & 63;
  float4 a = *(const float4*)&h[(size_t)row * EE + (lane << 2)];
  float4 w = *(const float4*)&sw[lane << 2];
  float s = (a.x * w.x + a.y * w.y) + (a.z * w.z + a.w * w.w);
#pragma unroll
  for (int m = 32; m > 0; m >>= 1) s += __shfl_xor(s, m);
  if (lane == 0) {
    float sc = s + sb[0];
    probs[row] = 1.0f / (1.0f + expf(-sc));
  }
}

// ---------------------------------------------------------------------------
// Per-graph exact top-k with jax.lax.top_k tie semantics (lower index wins).
// ---------------------------------------------------------------------------
__global__ __launch_bounds__(256) void topk_kernel(const float* __restrict__ probs,
                                                   float* __restrict__ out) {
  __shared__ unsigned long long keys[NNODE];
  __shared__ float pv[NNODE];
  __shared__ int flags[NNODE];
  __shared__ int sc[NNODE];
  const int g = blockIdx.x, tid = threadIdx.x;
  for (int i = tid; i < NNODE; i += 256) {
    float p = probs[g * NNODE + i];
    pv[i] = p;
    keys[i] = ((unsigned long long)__float_as_uint(p) << 32) |
              (unsigned long long)(~(unsigned)i);
    flags[i] = 0;
  }
  for (int k = 2; k <= NNODE; k <<= 1) {
    for (int j = k >> 1; j > 0; j >>= 1) {
      __syncthreads();
      for (int i = tid; i < NNODE; i += 256) {
        int ixj = i ^ j;
        if (ixj > i) {
          unsigned long long a = keys[i], bq = keys[ixj];
          bool desc = ((i & k) == 0);
          bool sw = desc ? (a < bq) : (a > bq);
          if (sw) { keys[i] = bq; keys[ixj] = a; }
        }
      }
    }
  }
  __syncthreads();
  if (tid < KSEL) {
    unsigned idx = ~(unsigned)(keys[tid] & 0xFFFFFFFFull);
    flags[idx] = 1;
  }
  __syncthreads();
  sc[tid] = flags[tid];
  sc[tid + 256] = flags[tid + 256];
  for (int off = 1; off < NNODE; off <<= 1) {
    __syncthreads();
    int x0 = (tid >= off) ? sc[tid - off] : 0;
    int x1 = sc[tid + 256 - off];
    int b0 = sc[tid], b1 = sc[tid + 256];
    __syncthreads();
    sc[tid] = b0 + x0;
    sc[tid + 256] = b1 + x1;
  }
  __syncthreads();
  for (int i = tid; i < NNODE; i += 256) {
    float p = pv[i];
    int f = flags[i];
    float ind = ((float)f - p) + p;
    float pf = p * ind;
    out[NEDGE + GG * KSEL + g * NNODE + i] = pf;
    if (f) out[NEDGE + g * KSEL + (sc[i] - 1)] = (float)(g * NNODE + i);
  }
}

// ---------------------------------------------------------------------------
__global__ __launch_bounds__(256) void edge_kernel(const int* __restrict__ ei,
                                                   const float* __restrict__ w,
                                                   float* __restrict__ out) {
  int e = blockIdx.x * 256 + threadIdx.x;
  const float* pf = out + NEDGE + GG * KSEL;
  out[e] = w[e] * pf[ei[e]] * pf[ei[NEDGE + e]];
}

// ---------------------------------------------------------------------------
extern "C" void kernel_launch(void* const* d_in, const int* in_sizes, int n_in,
                              void* d_out, int out_size, void* d_ws, size_t ws_size,
                              hipStream_t stream) {
  (void)in_sizes; (void)n_in; (void)out_size; (void)ws_size;
  const float* x     = (const float*)d_in[0];
  const int*   ei    = (const int*)d_in[1];
  const float* ewts  = (const float*)d_in[2];
  const float* emb_w = (const float*)d_in[3];
  const float* emb_b = (const float*)d_in[4];
  const float* qkv_w = (const float*)d_in[5];
  const float* qkv_b = (const float*)d_in[6];
  const float* out_w = (const float*)d_in[7];
  const float* out_b = (const float*)d_in[8];
  const float* ln1_w = (const float*)d_in[9];
  const float* ln1_b = (const float*)d_in[10];
  const float* ln2_w = (const float*)d_in[11];
  const float* ln2_b = (const float*)d_in[12];
  const float* ff1_w = (const float*)d_in[13];
  const float* ff1_b = (const float*)d_in[14];
  const float* ff2_w = (const float*)d_in[15];
  const float* ff2_b = (const float*)d_in[16];
  const float* sc_w  = (const float*)d_in[17];
  const float* sc_b  = (const float*)d_in[18];
  float* out = (float*)d_out;

  const size_t MB = 1024 * 1024;
  char* base = (char*)d_ws;
  float*  h    = (float*)base;                       // [0,32)
  ushort* h_hi = (ushort*)(base + 32 * MB);          // [32,48)
  ushort* h_lo = (ushort*)(base + 48 * MB);          // [48,64)
  char*   R    = base + 64 * MB;                     // [64,224) multi-use
  // attn phase:
  ushort* qkv_hi = (ushort*)R;                       // [64,112)
  ushort* qkv_lo = (ushort*)(R + 48 * MB);           // [112,160)
  ushort* o_hi   = (ushort*)(R + 96 * MB);           // [160,176)
  ushort* o_lo   = (ushort*)(R + 112 * MB);          // [176,192)
  ushort* vt_hi  = (ushort*)(R + 128 * MB);          // [192,208)
  ushort* vt_lo  = (ushort*)(R + 144 * MB);          // [208,224)
  // FFN phase (qkv/o/vt dead):
  ushort* t_hi   = (ushort*)R;                       // [64,128)  GN x 1024
  ushort* t_lo   = (ushort*)(R + 64 * MB);           // [128,192)
  float*  delta  = (float*)(R + 128 * MB);           // [192,224) GN x 256 fp32
  // embed phase:
  ushort* x_hi   = (ushort*)R;                       // [64,72)
  ushort* x_lo   = (ushort*)(R + 8 * MB);            // [72,80)
  float*  probs  = (float*)R;                        // final
  char* W = base + 224 * MB;
  size_t woff = 0;
  auto walloc = [&](size_t bytes) { char* r = W + woff; woff += (bytes + 255) & ~(size_t)255; return (ushort*)r; };
  ushort* we_hi = walloc(256 * 128 * 2);
  ushort* we_lo = walloc(256 * 128 * 2);
  ushort* wq_hi = walloc((size_t)LL * 768 * 256 * 2);
  ushort* wq_lo = walloc((size_t)LL * 768 * 256 * 2);
  ushort* wo_hi = walloc((size_t)LL * 256 * 256 * 2);
  ushort* wo_lo = walloc((size_t)LL * 256 * 256 * 2);
  ushort* w1_hi = walloc((size_t)LL * DFFN * 256 * 2);
  ushort* w1_lo = walloc((size_t)LL * DFFN * 256 * 2);
  ushort* w2_hi = walloc((size_t)LL * 256 * DFFN * 2);
  ushort* w2_lo = walloc((size_t)LL * 256 * DFFN * 2);

  auto split = [&](const float* src, ushort* hi, ushort* lo, size_t n) {
    int n4 = (int)(n / 4);
    split_kernel<<<(n4 + 255) / 256, 256, 0, stream>>>(src, hi, lo, n4);
  };
  split(x, x_hi, x_lo, (size_t)GN * DIN);
  split(emb_w, we_hi, we_lo, 256 * 128);
  split(qkv_w, wq_hi, wq_lo, (size_t)LL * 768 * 256);
  split(out_w, wo_hi, wo_lo, (size_t)LL * 256 * 256);
  split(ff1_w, w1_hi, w1_lo, (size_t)LL * DFFN * 256);
  split(ff2_w, w2_hi, w2_lo, (size_t)LL * 256 * DFFN);

  // ---- embed: h = x @ emb_w^T + emb_b (fp32 + split) ----
  mm_split<128, 128, 3, false, false, false><<<dim3(EE / 128, GN / 128), 256, 0, stream>>>(
      x_hi, x_lo, we_hi, we_lo, emb_b, h, h_hi, h_lo, nullptr, nullptr,
      GN, EE, DIN, DIN, DIN);

  for (int l = 0; l < LL; ++l) {
    // qkv (split out + fused V transpose)
    mm_split<128, 128, 2, false, true, false><<<dim3(768 / 128, GN / 128), 256, 0, stream>>>(
        h_hi, h_lo, wq_hi + (size_t)l * 768 * 256, wq_lo + (size_t)l * 768 * 256,
        qkv_b + l * 768, nullptr, qkv_hi, qkv_lo, vt_hi, vt_lo,
        GN, 768, EE, EE, EE);
    attn_mfma<<<dim3(4, 8, GG), 256, 0, stream>>>(qkv_hi, qkv_lo, vt_hi, vt_lo, o_hi, o_lo);
    // out-proj + residual + LN1 fused (K=256)
    mm_ln<<<GN / 32, 256, 0, stream>>>(
        o_hi, o_lo, wo_hi + (size_t)l * 256 * 256, wo_lo + (size_t)l * 256 * 256,
        out_b + l * 256, ln1_w + l * EE, ln1_b + l * EE, h, h_hi, h_lo, EE);
    // FFN sliced over DFF (2 slices of 1024): ff1 full-GN -> t, ff2 accumulates delta
    for (int s = 0; s < 2; ++s) {
      mm_split<128, 128, 2, true, false, false><<<dim3(1024 / 128, GN / 128), 256, 0, stream>>>(
          h_hi, h_lo,
          w1_hi + (size_t)l * DFFN * 256 + (size_t)s * 1024 * 256,
          w1_lo + (size_t)l * DFFN * 256 + (size_t)s * 1024 * 256,
          ff1_b + l * DFFN + s * 1024, nullptr, t_hi, t_lo, nullptr, nullptr,
          GN, 1024, EE, EE, EE);
      if (s == 0)
        mm_split<128, 128, 1, false, false, false><<<dim3(EE / 128, GN / 128), 256, 0, stream>>>(
            t_hi, t_lo,
            w2_hi + (size_t)l * 256 * DFFN, w2_lo + (size_t)l * 256 * DFFN,
            ff2_b + l * 256, delta, nullptr, nullptr, nullptr, nullptr,
            GN, EE, 1024, 1024, DFFN);
      else
        mm_split<128, 128, 1, false, false, true><<<dim3(EE / 128, GN / 128), 256, 0, stream>>>(
            t_hi, t_lo,
            w2_hi + (size_t)l * 256 * DFFN + 1024, w2_lo + (size_t)l * 256 * DFFN + 1024,
            ff2_b + l * 256, delta, nullptr, nullptr, nullptr, nullptr,
            GN, EE, 1024, 1024, DFFN);
    }
    ln_res_kernel<<<GN / 4, 256, 0, stream>>>(
        h, delta, ln2_w + l * EE, ln2_b + l * EE, h_hi, h_lo);
  }

  score_kernel<<<GN / 4, 256, 0, stream>>>(h, sc_w, sc_b, probs);
  topk_kernel<<<GG, 256, 0, stream>>>(probs, out);
  edge_kernel<<<NEDGE / 256, 256, 0, stream>>>(ei, ewts, out);
}

// Round 10
// 2647.076 us; speedup vs baseline: 1.0326x; 1.0326x over previous
//
#include <hip/hip_runtime.h>
#include <cstdint>
#include <cstddef>

#define GN    32768
#define GG    64
#define NNODE 512
#define EE    256
#define LL    4
#define DFFN  2048
#define NHH   8
#define HD    32
#define NEDGE 524288
#define KSEL  128
#define DIN   128

typedef __attribute__((ext_vector_type(8))) short short8;
typedef __attribute__((ext_vector_type(4))) float floatx4;

// ---- bf16 helpers (RNE) ---------------------------------------------------
__device__ __forceinline__ unsigned short f2bf(float x) {
  unsigned u = __float_as_uint(x);
  u = (u + 0x7FFFu + ((u >> 16) & 1u)) >> 16;
  return (unsigned short)u;
}
__device__ __forceinline__ float bf2f(unsigned short u) {
  return __uint_as_float((unsigned)u << 16);
}
__device__ __forceinline__ unsigned pack_split(float v) {
  unsigned short hb = f2bf(v);
  unsigned short lb = f2bf(v - bf2f(hb));
  return (unsigned)hb | ((unsigned)lb << 16);
}

// async global->LDS, 16B per lane (LDS dst must be wave-uniform base + lane*16)
__device__ __forceinline__ void ld_lds16(const ushort* g, ushort* l) {
  __builtin_amdgcn_global_load_lds(
      (const __attribute__((address_space(1))) unsigned int*)g,
      (__attribute__((address_space(3))) unsigned int*)l, 16, 0, 0);
}

// ---------------------------------------------------------------------------
// split fp32 -> (hi, lo) bf16 pair, 4 elements/thread
// ---------------------------------------------------------------------------
__global__ __launch_bounds__(256) void split_kernel(const float* __restrict__ in,
                                                    ushort* __restrict__ hi,
                                                    ushort* __restrict__ lo, int n4) {
  int i = blockIdx.x * 256 + threadIdx.x;
  if (i >= n4) return;
  float4 v = ((const float4*)in)[i];
  ushort4 hv, lv;
  float t[4] = {v.x, v.y, v.z, v.w};
  unsigned short hb;
  hb = f2bf(t[0]); hv.x = hb; lv.x = f2bf(t[0] - bf2f(hb));
  hb = f2bf(t[1]); hv.y = hb; lv.y = f2bf(t[1] - bf2f(hb));
  hb = f2bf(t[2]); hv.z = hb; lv.z = f2bf(t[2] - bf2f(hb));
  hb = f2bf(t[3]); hv.w = hb; lv.w = f2bf(t[3] - bf2f(hb));
  ((ushort4*)hi)[i] = hv;
  ((ushort4*)lo)[i] = lv;
}

// ---------------------------------------------------------------------------
// Split-bf16 MFMA GEMM: C[M,N] = split(A)[M,K] @ split(B)[N,K]^T (+bias / +=C)
// Strided A/B (lda/ldb) so K-slices of larger matrices can be addressed.
// XOR-swizzled LDS: frag b128 reads hit 8 banks (2-way, free).
// MODE bit0: fp32 C; bit1: split bf16 C. ACC: accumulate into Cf (no bias).
// VT: also scatter cols>=512 into vt[].
// ---------------------------------------------------------------------------
template <int BM, int BN, int MODE, bool RELU, bool VT, bool ACC>
__global__ __launch_bounds__(256) void mm_split(
    const ushort* __restrict__ a_hi, const ushort* __restrict__ a_lo,
    const ushort* __restrict__ b_hi, const ushort* __restrict__ b_lo,
    const float* __restrict__ bias,
    float* __restrict__ Cf, ushort* __restrict__ c_hi, ushort* __restrict__ c_lo,
    ushort* __restrict__ vth, ushort* __restrict__ vtl,
    int M, int N, int K, int lda, int ldb) {
  constexpr int MI = BM / 32;
  constexpr int NJ = BN / 32;
  __shared__ ushort As[2][BM * 32];
  __shared__ ushort Bs[2][BN * 32];
  const int tid = threadIdx.x;
  const int w = tid >> 6, lane = tid & 63;
  const int wm = (w >> 1) * (BM / 2), wn = (w & 1) * (BN / 2);
  const int bm = blockIdx.y * BM, bn = blockIdx.x * BN;
  const int lrow = lane & 15, lquad = lane >> 4;

  floatx4 acc[MI][NJ];
  floatx4 zz = {0.f, 0.f, 0.f, 0.f};
#pragma unroll
  for (int i = 0; i < MI; ++i)
#pragma unroll
    for (int j = 0; j < NJ; ++j) acc[i][j] = zz;

  const int arow = tid >> 2;
  const int acol = (((tid & 3) ^ ((arow >> 1) & 3)) << 3);  // swizzled source col
  const ushort* pah = a_hi + (size_t)(bm + arow) * lda + acol;
  const ushort* pal = a_lo + (size_t)(bm + arow) * lda + acol;
  const ushort* pbh = b_hi + (size_t)(bn + arow) * ldb + acol;
  const ushort* pbl = b_lo + (size_t)(bn + arow) * ldb + acol;

  for (int k0 = 0; k0 < K; k0 += 32) {
    __syncthreads();
#pragma unroll
    for (int s = 0; s < BM / 64; ++s) {
      ld_lds16(pah + (size_t)s * 64 * lda + k0, &As[0][s * 2048 + tid * 8]);
      ld_lds16(pal + (size_t)s * 64 * lda + k0, &As[1][s * 2048 + tid * 8]);
    }
#pragma unroll
    for (int s = 0; s < BN / 64; ++s) {
      ld_lds16(pbh + (size_t)s * 64 * ldb + k0, &Bs[0][s * 2048 + tid * 8]);
      ld_lds16(pbl + (size_t)s * 64 * ldb + k0, &Bs[1][s * 2048 + tid * 8]);
    }
    __syncthreads();
    short8 ah[MI], al[MI], bh[NJ], bl[NJ];
#pragma unroll
    for (int i = 0; i < MI; ++i) {
      int rr = wm + i * 16 + lrow;
      int r = rr * 32 + ((lquad ^ ((rr >> 1) & 3)) << 3);
      ah[i] = *(const short8*)&As[0][r];
      al[i] = *(const short8*)&As[1][r];
    }
#pragma unroll
    for (int j = 0; j < NJ; ++j) {
      int rr = wn + j * 16 + lrow;
      int r = rr * 32 + ((lquad ^ ((rr >> 1) & 3)) << 3);
      bh[j] = *(const short8*)&Bs[0][r];
      bl[j] = *(const short8*)&Bs[1][r];
    }
#pragma unroll
    for (int i = 0; i < MI; ++i)
#pragma unroll
      for (int j = 0; j < NJ; ++j) {
        acc[i][j] = __builtin_amdgcn_mfma_f32_16x16x32_bf16(al[i], bh[j], acc[i][j], 0, 0, 0);
        acc[i][j] = __builtin_amdgcn_mfma_f32_16x16x32_bf16(ah[i], bl[j], acc[i][j], 0, 0, 0);
        acc[i][j] = __builtin_amdgcn_mfma_f32_16x16x32_bf16(ah[i], bh[j], acc[i][j], 0, 0, 0);
      }
  }

#pragma unroll
  for (int j = 0; j < NJ; ++j) {
    int col = bn + wn + j * 16 + lrow;
    float bj = ACC ? 0.0f : bias[col];
#pragma unroll
    for (int i = 0; i < MI; ++i) {
      int row0 = bm + wm + i * 16 + lquad * 4;
#pragma unroll
      for (int r = 0; r < 4; ++r) {
        size_t off = (size_t)(row0 + r) * N + col;
        float v = acc[i][j][r] + bj;
        if constexpr (ACC) v += Cf[off];
        if (RELU) v = fmaxf(v, 0.0f);
        if constexpr (MODE & 1) Cf[off] = v;
        if constexpr (MODE & 2) {
          unsigned short hb = f2bf(v);
          unsigned short lb = f2bf(v - bf2f(hb));
          c_hi[off] = hb;
          c_lo[off] = lb;
          if constexpr (VT) {
            if (col >= 512) {
              int hd = col - 512;
              int row = row0 + r;
              size_t vo = ((size_t)((row >> 9) * 8 + (hd >> 5)) * 32 + (hd & 31)) * 512 + (row & 511);
              vth[vo] = hb;
              vtl[vo] = lb;
            }
          }
        }
      }
    }
  }
}

// ---------------------------------------------------------------------------
// Split GEMM + bias + residual + LayerNorm fused epilogue (BM=32; K=256
// out-proj only — for long K the barrier:MFMA ratio loses, measured r5-r7)
// ---------------------------------------------------------------------------
__global__ __launch_bounds__(256) void mm_ln(
    const ushort* __restrict__ a_hi, const ushort* __restrict__ a_lo,
    const ushort* __restrict__ b_hi, const ushort* __restrict__ b_lo,
    const float* __restrict__ bias, const float* __restrict__ lnw,
    const float* __restrict__ lnb, float* __restrict__ hbuf,
    ushort* __restrict__ hhi, ushort* __restrict__ hlo, int K) {
  __shared__ ushort As[2][32 * 32];
  __shared__ ushort Bs[2][256 * 32];
  __shared__ float rsum[32], rsq[32], muA[32], rsA[32];
  const int tid = threadIdx.x;
  const int w = tid >> 6, lane = tid & 63;
  const int wn = w * 64;
  const int bm = blockIdx.x * 32;
  const int lr = lane & 15, quad = lane >> 4;

  floatx4 acc[2][4];
  floatx4 zz = {0.f, 0.f, 0.f, 0.f};
#pragma unroll
  for (int i = 0; i < 2; ++i)
#pragma unroll
    for (int j = 0; j < 4; ++j) acc[i][j] = zz;

  if (tid < 32) { rsum[tid] = 0.f; rsq[tid] = 0.f; }

  const int aidx = tid & 127;
  const int arow = aidx >> 2;
  const int aacol = (((aidx & 3) ^ ((arow >> 1) & 3)) << 3);
  const ushort* pa = ((tid >> 7) ? a_lo : a_hi) + (size_t)(bm + arow) * K + aacol;
  ushort* adst = &As[tid >> 7][aidx * 8];
  const int brow = tid >> 2;
  const int bcol = (((tid & 3) ^ ((brow >> 1) & 3)) << 3);

  for (int k0 = 0; k0 < K; k0 += 32) {
    __syncthreads();
    ld_lds16(pa + k0, adst);
#pragma unroll
    for (int s = 0; s < 4; ++s) {
      ld_lds16(b_hi + (size_t)(s * 64 + brow) * K + bcol + k0, &Bs[0][s * 2048 + tid * 8]);
      ld_lds16(b_lo + (size_t)(s * 64 + brow) * K + bcol + k0, &Bs[1][s * 2048 + tid * 8]);
    }
    __syncthreads();
    short8 ah[2], al[2], bh[4], bl[4];
#pragma unroll
    for (int i = 0; i < 2; ++i) {
      int rr = i * 16 + lr;
      int r = rr * 32 + ((quad ^ ((rr >> 1) & 3)) << 3);
      ah[i] = *(const short8*)&As[0][r];
      al[i] = *(const short8*)&As[1][r];
    }
#pragma unroll
    for (int j = 0; j < 4; ++j) {
      int rr = wn + j * 16 + lr;
      int r = rr * 32 + ((quad ^ ((rr >> 1) & 3)) << 3);
      bh[j] = *(const short8*)&Bs[0][r];
      bl[j] = *(const short8*)&Bs[1][r];
    }
#pragma unroll
    for (int i = 0; i < 2; ++i)
#pragma unroll
      for (int j = 0; j < 4; ++j) {
        acc[i][j] = __builtin_amdgcn_mfma_f32_16x16x32_bf16(al[i], bh[j], acc[i][j], 0, 0, 0);
        acc[i][j] = __builtin_amdgcn_mfma_f32_16x16x32_bf16(ah[i], bl[j], acc[i][j], 0, 0, 0);
        acc[i][j] = __builtin_amdgcn_mfma_f32_16x16x32_bf16(ah[i], bh[j], acc[i][j], 0, 0, 0);
      }
  }

  // ---- epilogue: v = acc + bias + residual; row LN; write h + split ----
#pragma unroll
  for (int i = 0; i < 2; ++i) {
#pragma unroll
    for (int r = 0; r < 4; ++r) {
      int ridx = i * 16 + quad * 4 + r;
      float sp = 0.f, qp = 0.f;
#pragma unroll
      for (int j = 0; j < 4; ++j) {
        int col = wn + j * 16 + lr;
        float v = acc[i][j][r] + bias[col] + hbuf[(size_t)(bm + ridx) * EE + col];
        acc[i][j][r] = v;
        sp += v;
        qp += v * v;
      }
#pragma unroll
      for (int m = 1; m < 16; m <<= 1) { sp += __shfl_xor(sp, m); qp += __shfl_xor(qp, m); }
      if (lr == 0) { atomicAdd(&rsum[ridx], sp); atomicAdd(&rsq[ridx], qp); }
    }
  }
  __syncthreads();
  if (tid < 32) {
    float mu = rsum[tid] * (1.0f / 256.0f);
    float var = rsq[tid] * (1.0f / 256.0f) - mu * mu;
    muA[tid] = mu;
    rsA[tid] = 1.0f / sqrtf(var + 1e-5f);
  }
  __syncthreads();
#pragma unroll
  for (int i = 0; i < 2; ++i) {
#pragma unroll
    for (int r = 0; r < 4; ++r) {
      int ridx = i * 16 + quad * 4 + r;
      float mu = muA[ridx], rsv = rsA[ridx];
#pragma unroll
      for (int j = 0; j < 4; ++j) {
        int col = wn + j * 16 + lr;
        float o = (acc[i][j][r] - mu) * rsv * lnw[col] + lnb[col];
        size_t off = (size_t)(bm + ridx) * EE + col;
        hbuf[off] = o;
        unsigned short hb = f2bf(o);
        hhi[off] = hb;
        hlo[off] = f2bf(o - bf2f(hb));
      }
    }
  }
}

// ---------------------------------------------------------------------------
// h = LN(h + t)*w + b ; also writes split(h). One wave per row.
// ---------------------------------------------------------------------------
__global__ __launch_bounds__(256) void ln_res_kernel(float* __restrict__ h,
                                                     const float* __restrict__ t,
                                                     const float* __restrict__ w,
                                                     const float* __restrict__ b,
                                                     ushort* __restrict__ h_hi,
                                                     ushort* __restrict__ h_lo) {
  int row = blockIdx.x * 4 + (threadIdx.x >> 6);
  int lane = threadIdx.x & 63;
  size_t off = (size_t)row * EE + (lane << 2);
  float4 hv = *(const float4*)&h[off];
  float4 tv = *(const float4*)&t[off];
  float v0 = hv.x + tv.x, v1 = hv.y + tv.y, v2 = hv.z + tv.z, v3 = hv.w + tv.w;
  float s = (v0 + v1) + (v2 + v3);
#pragma unroll
  for (int m = 32; m > 0; m >>= 1) s += __shfl_xor(s, m);
  float mu = s * (1.0f / 256.0f);
  float d0 = v0 - mu, d1 = v1 - mu, d2 = v2 - mu, d3 = v3 - mu;
  float s2 = (d0 * d0 + d1 * d1) + (d2 * d2 + d3 * d3);
#pragma unroll
  for (int m = 32; m > 0; m >>= 1) s2 += __shfl_xor(s2, m);
  float rs = 1.0f / sqrtf(s2 * (1.0f / 256.0f) + 1e-5f);
  float4 wv = *(const float4*)&w[lane << 2];
  float4 bv = *(const float4*)&b[lane << 2];
  float4 o;
  o.x = d0 * rs * wv.x + bv.x;
  o.y = d1 * rs * wv.y + bv.y;
  o.z = d2 * rs * wv.z + bv.z;
  o.w = d3 * rs * wv.w + bv.w;
  *(float4*)&h[off] = o;
  ushort4 hb4, lb4;
  unsigned short hb;
  hb = f2bf(o.x); hb4.x = hb; lb4.x = f2bf(o.x - bf2f(hb));
  hb = f2bf(o.y); hb4.y = hb; lb4.y = f2bf(o.y - bf2f(hb));
  hb = f2bf(o.z); hb4.z = hb; lb4.z = f2bf(o.z - bf2f(hb));
  hb = f2bf(o.w); hb4.w = hb; lb4.w = f2bf(o.w - bf2f(hb));
  *(ushort4*)&h_hi[off] = hb4;
  *(ushort4*)&h_lo[off] = lb4;
}

// ---------------------------------------------------------------------------
// MFMA flash attention — best-measured structure (r7 bench: 142.7 us):
// q-tile 64, ONE 16-row m-tile per wave, 64-key K-tiles, slim LDS (~36.9 KB)
// -> 4 blocks/CU, VGPR ~56, grid (qt, hh, g). Plus exp2-domain softmax
// (scale*log2e folded into S; proven in r9) — strict VALU reduction.
// Do NOT: hoist S across m-tiles (r5), chunk softmax <128 keys (r4),
// 2 m-tiles/block (r9), (gh,qt) grid (r8) — all measured regressions.
// ---------------------------------------------------------------------------
__global__ __launch_bounds__(256) void attn_mfma(const ushort* __restrict__ qh,
                                                 const ushort* __restrict__ ql,
                                                 const ushort* __restrict__ vth,
                                                 const ushort* __restrict__ vtl,
                                                 ushort* __restrict__ o_hi,
                                                 ushort* __restrict__ o_lo) {
  __shared__ ushort Ks[2][64 * 40];
  __shared__ ushort Vt[2][32 * 72];
  __shared__ unsigned Pint[4][16 * 68];
  const int tid = threadIdx.x;
  const int w = tid >> 6, lane = tid & 63, c = lane & 15, quad = lane >> 4;
  const int qt = blockIdx.x, hh = blockIdx.y, g = blockIdx.z;
  const size_t g512 = (size_t)g * 512;
  const size_t vtbase = (size_t)(g * 8 + hh) * 32 * 512;
  const float scale = 0.17677669529663687f * 1.44269504088896340f;  // /sqrt(32)*log2e

  const size_t qnode = g512 + qt * 64 + w * 16 + c;
  short8 qfh = *(const short8*)(qh + qnode * 768 + hh * 32 + quad * 8);
  short8 qfl = *(const short8*)(ql + qnode * 768 + hh * 32 + quad * 8);

  floatx4 O0 = {0.f, 0.f, 0.f, 0.f}, O1 = {0.f, 0.f, 0.f, 0.f};
  float mrow[4] = {-3e38f, -3e38f, -3e38f, -3e38f};
  float lrow[4] = {0.f, 0.f, 0.f, 0.f};

  const int skey = tid >> 2, sdc = (tid & 3) << 3;
  const int sd = tid >> 3, skc = (tid & 7) << 3;
  short8 stg[4];
  auto load_tile = [&](int kb) {
    size_t go = (g512 + kb + skey) * 768 + 256 + hh * 32 + sdc;
    stg[0] = *(const short8*)(qh + go);
    stg[1] = *(const short8*)(ql + go);
    size_t vo = vtbase + (size_t)sd * 512 + kb + skc;
    stg[2] = *(const short8*)(vth + vo);
    stg[3] = *(const short8*)(vtl + vo);
  };
  load_tile(0);

  for (int t = 0; t < 8; ++t) {
    if (t) __syncthreads();
    *(short8*)&Ks[0][skey * 40 + sdc] = stg[0];
    *(short8*)&Ks[1][skey * 40 + sdc] = stg[1];
    *(short8*)&Vt[0][sd * 72 + skc] = stg[2];
    *(short8*)&Vt[1][sd * 72 + skc] = stg[3];
    __syncthreads();
    if (t < 7) load_tile((t + 1) * 64);

    // ---- S = (Q K^T) * scale : 4 n-tiles of 16x16 ----
    floatx4 S[4];
#pragma unroll
    for (int n = 0; n < 4; ++n) {
      int r = (n * 16 + c) * 40 + quad * 8;
      short8 kfh = *(const short8*)&Ks[0][r];
      short8 kfl = *(const short8*)&Ks[1][r];
      floatx4 s = {0.f, 0.f, 0.f, 0.f};
      s = __builtin_amdgcn_mfma_f32_16x16x32_bf16(qfh, kfl, s, 0, 0, 0);
      s = __builtin_amdgcn_mfma_f32_16x16x32_bf16(qfl, kfh, s, 0, 0, 0);
      s = __builtin_amdgcn_mfma_f32_16x16x32_bf16(qfh, kfh, s, 0, 0, 0);
#pragma unroll
      for (int r2 = 0; r2 < 4; ++r2) s[r2] *= scale;
      S[n] = s;
    }
    // ---- online softmax (rows = quad*4 + r, per-lane state, exp2 domain) ----
    float corr[4];
#pragma unroll
    for (int r = 0; r < 4; ++r) {
      float mx = S[0][r];
#pragma unroll
      for (int n = 1; n < 4; ++n) mx = fmaxf(mx, S[n][r]);
#pragma unroll
      for (int msk = 1; msk < 16; msk <<= 1) mx = fmaxf(mx, __shfl_xor(mx, msk));
      float mn = fmaxf(mrow[r], mx);
      corr[r] = exp2f(mrow[r] - mn);
      mrow[r] = mn;
    }
    float rs[4] = {0.f, 0.f, 0.f, 0.f};
#pragma unroll
    for (int n = 0; n < 4; ++n) {
#pragma unroll
      for (int r = 0; r < 4; ++r) {
        float pp = exp2f(S[n][r] - mrow[r]);
        rs[r] += pp;
        Pint[w][(quad * 4 + r) * 68 + n * 16 + c] = pack_split(pp);
      }
    }
#pragma unroll
    for (int r = 0; r < 4; ++r) {
      float t2 = rs[r];
#pragma unroll
      for (int msk = 1; msk < 16; msk <<= 1) t2 += __shfl_xor(t2, msk);
      lrow[r] = lrow[r] * corr[r] + t2;
      O0[r] *= corr[r];
      O1[r] *= corr[r];
    }
    // ---- PV: O += P @ V  (2 d-tiles x 2 k-steps, 3-term split) ----
#pragma unroll
    for (int ks = 0; ks < 2; ++ks) {
      const unsigned* pp = &Pint[w][c * 68 + ks * 32 + quad * 8];
      uint4 a = *(const uint4*)pp;
      uint4 b = *(const uint4*)(pp + 4);
      union { short8 s; unsigned u[4]; } ph, pl;
      ph.u[0] = (a.x & 0xFFFFu) | (a.y << 16);
      ph.u[1] = (a.z & 0xFFFFu) | (a.w << 16);
      ph.u[2] = (b.x & 0xFFFFu) | (b.y << 16);
      ph.u[3] = (b.z & 0xFFFFu) | (b.w << 16);
      pl.u[0] = (a.x >> 16) | (a.y & 0xFFFF0000u);
      pl.u[1] = (a.z >> 16) | (a.w & 0xFFFF0000u);
      pl.u[2] = (b.x >> 16) | (b.y & 0xFFFF0000u);
      pl.u[3] = (b.z >> 16) | (b.w & 0xFFFF0000u);
      int r0 = c * 72 + ks * 32 + quad * 8;
      int r1 = (16 + c) * 72 + ks * 32 + quad * 8;
      short8 v0h = *(const short8*)&Vt[0][r0];
      short8 v0l = *(const short8*)&Vt[1][r0];
      short8 v1h = *(const short8*)&Vt[0][r1];
      short8 v1l = *(const short8*)&Vt[1][r1];
      O0 = __builtin_amdgcn_mfma_f32_16x16x32_bf16(ph.s, v0l, O0, 0, 0, 0);
      O0 = __builtin_amdgcn_mfma_f32_16x16x32_bf16(pl.s, v0h, O0, 0, 0, 0);
      O0 = __builtin_amdgcn_mfma_f32_16x16x32_bf16(ph.s, v0h, O0, 0, 0, 0);
      O1 = __builtin_amdgcn_mfma_f32_16x16x32_bf16(ph.s, v1l, O1, 0, 0, 0);
      O1 = __builtin_amdgcn_mfma_f32_16x16x32_bf16(pl.s, v1h, O1, 0, 0, 0);
      O1 = __builtin_amdgcn_mfma_f32_16x16x32_bf16(ph.s, v1h, O1, 0, 0, 0);
    }
  }

  // ---- epilogue: normalize, split, store ----
#pragma unroll
  for (int r = 0; r < 4; ++r) {
    float inv = 1.0f / lrow[r];
    size_t node = g512 + qt * 64 + w * 16 + quad * 4 + r;
    size_t off0 = node * EE + hh * 32 + c;
    float v0 = O0[r] * inv;
    float v1 = O1[r] * inv;
    unsigned short hb0 = f2bf(v0), hb1 = f2bf(v1);
    o_hi[off0] = hb0;       o_lo[off0] = f2bf(v0 - bf2f(hb0));
    o_hi[off0 + 16] = hb1;  o_lo[off0 + 16] = f2bf(v1 - bf2f(hb1));
  }
}

// ---------------------------------------------------------------------------
__global__ __launch_bounds__(256) void score_kernel(const float* __restrict__ h,
                                                    const float* __restrict__ sw,
                                                    const float* __restrict__ sb,
                                                    float* __restrict__ probs) {
  int row = blockIdx.x * 4 + (threadIdx.x >> 6);
  int lane = threadIdx.x & 63;
  float4 a = *(const float4*)&h[(size_t)row * EE + (lane << 2)];
  float4 w = *(const float4*)&sw[lane << 2];
  float s = (a.x * w.x + a.y * w.y) + (a.z * w.z + a.w * w.w);
#pragma unroll
  for (int m = 32; m > 0; m >>= 1) s += __shfl_xor(s, m);
  if (lane == 0) {
    float sc = s + sb[0];
    probs[row] = 1.0f / (1.0f + expf(-sc));
  }
}

// ---------------------------------------------------------------------------
// Per-graph exact top-k with jax.lax.top_k tie semantics (lower index wins).
// ---------------------------------------------------------------------------
__global__ __launch_bounds__(256) void topk_kernel(const float* __restrict__ probs,
                                                   float* __restrict__ out) {
  __shared__ unsigned long long keys[NNODE];
  __shared__ float pv[NNODE];
  __shared__ int flags[NNODE];
  __shared__ int sc[NNODE];
  const int g = blockIdx.x, tid = threadIdx.x;
  for (int i = tid; i < NNODE; i += 256) {
    float p = probs[g * NNODE + i];
    pv[i] = p;
    keys[i] = ((unsigned long long)__float_as_uint(p) << 32) |
              (unsigned long long)(~(unsigned)i);
    flags[i] = 0;
  }
  for (int k = 2; k <= NNODE; k <<= 1) {
    for (int j = k >> 1; j > 0; j >>= 1) {
      __syncthreads();
      for (int i = tid; i < NNODE; i += 256) {
        int ixj = i ^ j;
        if (ixj > i) {
          unsigned long long a = keys[i], bq = keys[ixj];
          bool desc = ((i & k) == 0);
          bool sw = desc ? (a < bq) : (a > bq);
          if (sw) { keys[i] = bq; keys[ixj] = a; }
        }
      }
    }
  }
  __syncthreads();
  if (tid < KSEL) {
    unsigned idx = ~(unsigned)(keys[tid] & 0xFFFFFFFFull);
    flags[idx] = 1;
  }
  __syncthreads();
  sc[tid] = flags[tid];
  sc[tid + 256] = flags[tid + 256];
  for (int off = 1; off < NNODE; off <<= 1) {
    __syncthreads();
    int x0 = (tid >= off) ? sc[tid - off] : 0;
    int x1 = sc[tid + 256 - off];
    int b0 = sc[tid], b1 = sc[tid + 256];
    __syncthreads();
    sc[tid] = b0 + x0;
    sc[tid + 256] = b1 + x1;
  }
  __syncthreads();
  for (int i = tid; i < NNODE; i += 256) {
    float p = pv[i];
    int f = flags[i];
    float ind = ((float)f - p) + p;
    float pf = p * ind;
    out[NEDGE + GG * KSEL + g * NNODE + i] = pf;
    if (f) out[NEDGE + g * KSEL + (sc[i] - 1)] = (float)(g * NNODE + i);
  }
}

// ---------------------------------------------------------------------------
__global__ __launch_bounds__(256) void edge_kernel(const int* __restrict__ ei,
                                                   const float* __restrict__ w,
                                                   float* __restrict__ out) {
  int e = blockIdx.x * 256 + threadIdx.x;
  const float* pf = out + NEDGE + GG * KSEL;
  out[e] = w[e] * pf[ei[e]] * pf[ei[NEDGE + e]];
}

// ---------------------------------------------------------------------------
extern "C" void kernel_launch(void* const* d_in, const int* in_sizes, int n_in,
                              void* d_out, int out_size, void* d_ws, size_t ws_size,
                              hipStream_t stream) {
  (void)in_sizes; (void)n_in; (void)out_size; (void)ws_size;
  const float* x     = (const float*)d_in[0];
  const int*   ei    = (const int*)d_in[1];
  const float* ewts  = (const float*)d_in[2];
  const float* emb_w = (const float*)d_in[3];
  const float* emb_b = (const float*)d_in[4];
  const float* qkv_w = (const float*)d_in[5];
  const float* qkv_b = (const float*)d_in[6];
  const float* out_w = (const float*)d_in[7];
  const float* out_b = (const float*)d_in[8];
  const float* ln1_w = (const float*)d_in[9];
  const float* ln1_b = (const float*)d_in[10];
  const float* ln2_w = (const float*)d_in[11];
  const float* ln2_b = (const float*)d_in[12];
  const float* ff1_w = (const float*)d_in[13];
  const float* ff1_b = (const float*)d_in[14];
  const float* ff2_w = (const float*)d_in[15];
  const float* ff2_b = (const float*)d_in[16];
  const float* sc_w  = (const float*)d_in[17];
  const float* sc_b  = (const float*)d_in[18];
  float* out = (float*)d_out;

  const size_t MB = 1024 * 1024;
  char* base = (char*)d_ws;
  float*  h    = (float*)base;                       // [0,32)
  ushort* h_hi = (ushort*)(base + 32 * MB);          // [32,48)
  ushort* h_lo = (ushort*)(base + 48 * MB);          // [48,64)
  char*   R    = base + 64 * MB;                     // [64,224) multi-use
  // attn phase:
  ushort* qkv_hi = (ushort*)R;                       // [64,112)
  ushort* qkv_lo = (ushort*)(R + 48 * MB);           // [112,160)
  ushort* o_hi   = (ushort*)(R + 96 * MB);           // [160,176)
  ushort* o_lo   = (ushort*)(R + 112 * MB);          // [176,192)
  ushort* vt_hi  = (ushort*)(R + 128 * MB);          // [192,208)
  ushort* vt_lo  = (ushort*)(R + 144 * MB);          // [208,224)
  // FFN phase (qkv/o/vt dead):
  ushort* t_hi   = (ushort*)R;                       // [64,128)  GN x 1024
  ushort* t_lo   = (ushort*)(R + 64 * MB);           // [128,192)
  float*  delta  = (float*)(R + 128 * MB);           // [192,224) GN x 256 fp32
  // embed phase:
  ushort* x_hi   = (ushort*)R;                       // [64,72)
  ushort* x_lo   = (ushort*)(R + 8 * MB);            // [72,80)
  float*  probs  = (float*)R;                        // final
  char* W = base + 224 * MB;
  size_t woff = 0;
  auto walloc = [&](size_t bytes) { char* r = W + woff; woff += (bytes + 255) & ~(size_t)255; return (ushort*)r; };
  ushort* we_hi = walloc(256 * 128 * 2);
  ushort* we_lo = walloc(256 * 128 * 2);
  ushort* wq_hi = walloc((size_t)LL * 768 * 256 * 2);
  ushort* wq_lo = walloc((size_t)LL * 768 * 256 * 2);
  ushort* wo_hi = walloc((size_t)LL * 256 * 256 * 2);
  ushort* wo_lo = walloc((size_t)LL * 256 * 256 * 2);
  ushort* w1_hi = walloc((size_t)LL * DFFN * 256 * 2);
  ushort* w1_lo = walloc((size_t)LL * DFFN * 256 * 2);
  ushort* w2_hi = walloc((size_t)LL * 256 * DFFN * 2);
  ushort* w2_lo = walloc((size_t)LL * 256 * DFFN * 2);

  auto split = [&](const float* src, ushort* hi, ushort* lo, size_t n) {
    int n4 = (int)(n / 4);
    split_kernel<<<(n4 + 255) / 256, 256, 0, stream>>>(src, hi, lo, n4);
  };
  split(x, x_hi, x_lo, (size_t)GN * DIN);
  split(emb_w, we_hi, we_lo, 256 * 128);
  split(qkv_w, wq_hi, wq_lo, (size_t)LL * 768 * 256);
  split(out_w, wo_hi, wo_lo, (size_t)LL * 256 * 256);
  split(ff1_w, w1_hi, w1_lo, (size_t)LL * DFFN * 256);
  split(ff2_w, w2_hi, w2_lo, (size_t)LL * 256 * DFFN);

  // ---- embed: h = x @ emb_w^T + emb_b (fp32 + split) ----
  mm_split<128, 128, 3, false, false, false><<<dim3(EE / 128, GN / 128), 256, 0, stream>>>(
      x_hi, x_lo, we_hi, we_lo, emb_b, h, h_hi, h_lo, nullptr, nullptr,
      GN, EE, DIN, DIN, DIN);

  for (int l = 0; l < LL; ++l) {
    // qkv (split out + fused V transpose)
    mm_split<128, 128, 2, false, true, false><<<dim3(768 / 128, GN / 128), 256, 0, stream>>>(
        h_hi, h_lo, wq_hi + (size_t)l * 768 * 256, wq_lo + (size_t)l * 768 * 256,
        qkv_b + l * 768, nullptr, qkv_hi, qkv_lo, vt_hi, vt_lo,
        GN, 768, EE, EE, EE);
    attn_mfma<<<dim3(8, 8, GG), 256, 0, stream>>>(qkv_hi, qkv_lo, vt_hi, vt_lo, o_hi, o_lo);
    // out-proj + residual + LN1 fused (K=256)
    mm_ln<<<GN / 32, 256, 0, stream>>>(
        o_hi, o_lo, wo_hi + (size_t)l * 256 * 256, wo_lo + (size_t)l * 256 * 256,
        out_b + l * 256, ln1_w + l * EE, ln1_b + l * EE, h, h_hi, h_lo, EE);
    // FFN sliced over DFF (2 slices of 1024): ff1 full-GN -> t, ff2 accumulates delta
    for (int s = 0; s < 2; ++s) {
      mm_split<128, 128, 2, true, false, false><<<dim3(1024 / 128, GN / 128), 256, 0, stream>>>(
          h_hi, h_lo,
          w1_hi + (size_t)l * DFFN * 256 + (size_t)s * 1024 * 256,
          w1_lo + (size_t)l * DFFN * 256 + (size_t)s * 1024 * 256,
          ff1_b + l * DFFN + s * 1024, nullptr, t_hi, t_lo, nullptr, nullptr,
          GN, 1024, EE, EE, EE);
      if (s == 0)
        mm_split<128, 128, 1, false, false, false><<<dim3(EE / 128, GN / 128), 256, 0, stream>>>(
            t_hi, t_lo,
            w2_hi + (size_t)l * 256 * DFFN, w2_lo + (size_t)l * 256 * DFFN,
            ff2_b + l * 256, delta, nullptr, nullptr, nullptr, nullptr,
            GN, EE, 1024, 1024, DFFN);
      else
        mm_split<128, 128, 1, false, false, true><<<dim3(EE / 128, GN / 128), 256, 0, stream>>>(
            t_hi, t_lo,
            w2_hi + (size_t)l * 256 * DFFN + 1024, w2_lo + (size_t)l * 256 * DFFN + 1024,
            ff2_b + l * 256, delta, nullptr, nullptr, nullptr, nullptr,
            GN, EE, 1024, 1024, DFFN);
    }
    ln_res_kernel<<<GN / 4, 256, 0, stream>>>(
        h, delta, ln2_w + l * EE, ln2_b + l * EE, h_hi, h_lo);
  }

  score_kernel<<<GN / 4, 256, 0, stream>>>(h, sc_w, sc_b, probs);
  topk_kernel<<<GG, 256, 0, stream>>>(probs, out);
  edge_kernel<<<NEDGE / 256, 256, 0, stream>>>(ei, ewts, out);
}